// Round 2
// baseline (5876.177 us; speedup 1.0000x reference)
//
#include <hip/hip_runtime.h>

// NonLocalMeans: rgb (8,3,1024,1024) f32, search 11x11, patch 5x5, circular.
// out(p) = sum_s w(p,s)*rgb(p-s) / sum_s w(p,s),
// w(p,s) = exp(-sqrt(box5x5((y - y_shift)^2)) * inv_h)
//
// R2 design:
//  - Expand the square: box((y-y')^2) = A(p) + A(p-s) - 2*Cross, where
//    A = box5x5(y^2) is shift-INDEPENDENT -> precomputed once into ldsA.
//    Row work drops 110 -> 55 VALU ops (pure 5-tap correlation).
//    fmaxf(s,0) guards sqrt of the tiny negative from cancellation at s=0.
//  - Fit the 64-VGPR cap by construction (both waves_per_eu attempts failed;
//    WRITE_SIZE proved ~17 spilled floats/dy-iter): dx split into two passes
//    (J=0..5, J=6..10) -> peak vertical partials 44 -> 24; w-window slides in
//    5 registers via argument permutation. Peak live ~60 VGPRs.
//  - ldsC float4 -> 3 float planes (saves 7 KB): total LDS 37 KB, 4 blocks/CU.
//  - Accumulation order (dy asc, dx asc, rows asc) identical to R1/reference.

#define HW (1024 * 1024)
#define W 1024
#define MASK 1023

constexpr int TILE = 32;
constexpr int YREG = 46;    // TILE + 2*7 (shift 5 + patch 2)
constexpr int YPITCH = 48;
constexpr int AREG = 42;    // TILE + 2*5
// -log2(e) / (1.0 + 1e-6)
constexpr float NEG_C = -1.4426935981939074f;

// 5-tap correlation of c0..c4 (in scope) with the 5 window args, ascending c.
#define CR5(W0,W1,W2,W3,W4) \
    fmaf(c4,(W4), fmaf(c3,(W3), fmaf(c2,(W2), fmaf(c1,(W1), c0*(W0)))))

// ---- per-J partial update sets (J is a literal; pX_J are named scalars) ----
#define OPS_S0(J)     p0_##J  = h
#define OPS_A0S1(J)   p0_##J += h; p1_##J  = h
#define OPS_A01S2(J)  p0_##J += h; p1_##J += h; p2_##J  = h
#define OPS_A012S3(J) p0_##J += h; p1_##J += h; p2_##J += h; p3_##J  = h
#define OPS_A0123(J)  p0_##J += h; p1_##J += h; p2_##J += h; p3_##J += h
#define OPS_A123(J)                p1_##J += h; p2_##J += h; p3_##J += h
#define OPS_A23(J)                              p2_##J += h; p3_##J += h
#define OPS_A3(J)                                            p3_##J += h

// Pass A: J = 5..0 (dx = 0..-5), w-window ywp[5..9] sliding up to ywp[10..14].
#define PA_ROW(RR, OPS) do {                                                \
    const float* ycp = &ldsY[(y0 + 5 + (RR)) * YPITCH + tx + 5];            \
    const float* ywp = &ldsY[(y0 + 5 + (RR) - dy) * YPITCH + tx];           \
    const float c0=ycp[0],c1=ycp[1],c2=ycp[2],c3=ycp[3],c4=ycp[4];          \
    float wa=ywp[5], wb=ywp[6], wc=ywp[7], wd=ywp[8], we=ywp[9], h;         \
    h = CR5(wa,wb,wc,wd,we); OPS(5);                                        \
    wa = ywp[10]; h = CR5(wb,wc,wd,we,wa); OPS(4);                          \
    wb = ywp[11]; h = CR5(wc,wd,we,wa,wb); OPS(3);                          \
    wc = ywp[12]; h = CR5(wd,we,wa,wb,wc); OPS(2);                          \
    wd = ywp[13]; h = CR5(we,wa,wb,wc,wd); OPS(1);                          \
    we = ywp[14]; h = CR5(wa,wb,wc,wd,we); OPS(0);                          \
} while (0)

// Pass B: J = 10..6 (dx = 5..1), w-window ywp[0..4] sliding up to ywp[4..8].
#define PB_ROW(RR, OPS) do {                                                \
    const float* ycp = &ldsY[(y0 + 5 + (RR)) * YPITCH + tx + 5];            \
    const float* ywp = &ldsY[(y0 + 5 + (RR) - dy) * YPITCH + tx];           \
    const float c0=ycp[0],c1=ycp[1],c2=ycp[2],c3=ycp[3],c4=ycp[4];          \
    float wa=ywp[0], wb=ywp[1], wc=ywp[2], wd=ywp[3], we=ywp[4], h;         \
    h = CR5(wa,wb,wc,wd,we); OPS(10);                                       \
    wa = ywp[5]; h = CR5(wb,wc,wd,we,wa); OPS(9);                           \
    wb = ywp[6]; h = CR5(wc,wd,we,wa,wb); OPS(8);                           \
    wc = ywp[7]; h = CR5(wd,we,wa,wb,wc); OPS(7);                           \
    wd = ywp[8]; h = CR5(we,wa,wb,wc,wd); OPS(6);                           \
} while (0)

// finalize one (output row, J): S = Ac + Aw - 2*Cross, clamp, sqrt, exp2, acc
#define FIN1(YO, J) do {                                                    \
    float s = fmaf(-2.0f, p##YO##_##J, acb + arow[-(J)]);                   \
    s = fmaxf(s, 0.0f);                                                     \
    float dist = __builtin_amdgcn_sqrtf(s);                                 \
    float wgt  = __builtin_amdgcn_exp2f(dist * NEG_C);                      \
    aR##YO = fmaf(wgt, rrow[-(J)], aR##YO);                                 \
    aG##YO = fmaf(wgt, grow[-(J)], aG##YO);                                 \
    aB##YO = fmaf(wgt, brow[-(J)], aB##YO);                                 \
    aW##YO += wgt;                                                          \
} while (0)

#define FIN_HEAD(YO)                                                        \
    const int sro = (y0 + (YO) - dy + 5) * AREG + tx + 10;                  \
    const float* arow = &ldsA[sro];                                         \
    const float* rrow = &ldsR[sro];                                         \
    const float* grow = &ldsG[sro];                                         \
    const float* brow = &ldsB[sro];                                         \
    const float acb = ldsA[(y0 + (YO) + 5) * AREG + tx + 5];

#define FIN_A(YO) do { FIN_HEAD(YO)                                         \
    FIN1(YO,0); FIN1(YO,1); FIN1(YO,2);                                     \
    FIN1(YO,3); FIN1(YO,4); FIN1(YO,5);                                     \
} while (0)

#define FIN_B(YO) do { FIN_HEAD(YO)                                         \
    FIN1(YO,6); FIN1(YO,7); FIN1(YO,8);                                     \
    FIN1(YO,9); FIN1(YO,10);                                                \
} while (0)

#define STORE(YO) do {                                                      \
    const int off = (by0 + y0 + (YO)) * W + bx0 + tx;                       \
    const float inv = 1.0f / aW##YO;                                        \
    obase[off]          = aR##YO * inv;                                     \
    obase[off + HW]     = aG##YO * inv;                                     \
    obase[off + 2 * HW] = aB##YO * inv;                                     \
} while (0)

// squared 5-tap row sum for the A-field precompute
#define A5(p) fmaf((p)[4],(p)[4], fmaf((p)[3],(p)[3], fmaf((p)[2],(p)[2],   \
              fmaf((p)[1],(p)[1], (p)[0]*(p)[0]))))

__attribute__((amdgpu_waves_per_eu(4, 4)))
__global__ void __launch_bounds__(256)
nlm_fused(const float* __restrict__ rgb, float* __restrict__ out) {
    __shared__ float ldsY[YREG * YPITCH];   // 8832 B
    __shared__ float ldsA[AREG * AREG];     // 7056 B  box5x5(y^2)
    __shared__ float ldsR[AREG * AREG];     // 7056 B
    __shared__ float ldsG[AREG * AREG];     // 7056 B
    __shared__ float ldsB[AREG * AREG];     // 7056 B   total 37056 B

    const int tid = threadIdx.x;
    const int batch = blockIdx.z;
    const int by0 = blockIdx.y * TILE;
    const int bx0 = blockIdx.x * TILE;

    const float* base = rgb + (size_t)batch * 3 * HW;

    // ---- stage luminance tile (mean over channels), halo 7 ----
    for (int i = tid; i < YREG * YREG; i += 256) {
        int ry = i / YREG, rx = i - ry * YREG;
        int gy = (by0 + ry - 7) & MASK;
        int gx = (bx0 + rx - 7) & MASK;
        int off = gy * W + gx;
        float v = (base[off] + base[off + HW] + base[off + 2 * HW]) * (1.0f / 3.0f);
        ldsY[ry * YPITCH + rx] = v;
    }
    // ---- stage rgb planes, halo 5 ----
    for (int i = tid; i < AREG * AREG; i += 256) {
        int ry = i / AREG, rx = i - ry * AREG;
        int gy = (by0 + ry - 5) & MASK;
        int gx = (bx0 + rx - 5) & MASK;
        int off = gy * W + gx;
        ldsR[i] = base[off];
        ldsG[i] = base[off + HW];
        ldsB[i] = base[off + 2 * HW];
    }
    __syncthreads();

    // ---- A = box5x5(y^2) over the 42x42 (halo 5) region ----
    for (int i = tid; i < AREG * AREG; i += 256) {
        int ry = i / AREG, rx = i - ry * AREG;
        const float* yb = &ldsY[ry * YPITCH + rx];
        float s =  A5(yb);
        s += A5(yb + YPITCH);
        s += A5(yb + 2 * YPITCH);
        s += A5(yb + 3 * YPITCH);
        s += A5(yb + 4 * YPITCH);
        ldsA[i] = s;
    }
    __syncthreads();

    const int tx = tid & 31;          // output column within tile
    const int y0 = (tid >> 5) * 4;    // 4-pixel column run per thread

    float aR0=0.f, aG0=0.f, aB0=0.f, aW0=0.f;
    float aR1=0.f, aG1=0.f, aB1=0.f, aW1=0.f;
    float aR2=0.f, aG2=0.f, aB2=0.f, aW2=0.f;
    float aR3=0.f, aG3=0.f, aB3=0.f, aW3=0.f;

    // vertical cross-correlation partials; pass A uses _0.._5, pass B _6.._10
    float p0_0,p0_1,p0_2,p0_3,p0_4,p0_5,p0_6,p0_7,p0_8,p0_9,p0_10;
    float p1_0,p1_1,p1_2,p1_3,p1_4,p1_5,p1_6,p1_7,p1_8,p1_9,p1_10;
    float p2_0,p2_1,p2_2,p2_3,p2_4,p2_5,p2_6,p2_7,p2_8,p2_9,p2_10;
    float p3_0,p3_1,p3_2,p3_3,p3_4,p3_5,p3_6,p3_7,p3_8,p3_9,p3_10;

    #pragma clang loop unroll(disable)
    for (int dy = -5; dy <= 5; ++dy) {
        // ---- pass A: dx = -5..0 (J = 0..5) ----
        PA_ROW(0, OPS_S0);
        PA_ROW(1, OPS_A0S1);
        PA_ROW(2, OPS_A01S2);
        PA_ROW(3, OPS_A012S3);
        PA_ROW(4, OPS_A0123);  FIN_A(0);
        PA_ROW(5, OPS_A123);   FIN_A(1);
        PA_ROW(6, OPS_A23);    FIN_A(2);
        PA_ROW(7, OPS_A3);     FIN_A(3);
        // ---- pass B: dx = 1..5 (J = 6..10) ----
        PB_ROW(0, OPS_S0);
        PB_ROW(1, OPS_A0S1);
        PB_ROW(2, OPS_A01S2);
        PB_ROW(3, OPS_A012S3);
        PB_ROW(4, OPS_A0123);  FIN_B(0);
        PB_ROW(5, OPS_A123);   FIN_B(1);
        PB_ROW(6, OPS_A23);    FIN_B(2);
        PB_ROW(7, OPS_A3);     FIN_B(3);
    }

    float* obase = out + (size_t)batch * 3 * HW;
    STORE(0);
    STORE(1);
    STORE(2);
    STORE(3);
}

extern "C" void kernel_launch(void* const* d_in, const int* in_sizes, int n_in,
                              void* d_out, int out_size, void* d_ws, size_t ws_size,
                              hipStream_t stream) {
    const float* rgb = (const float*)d_in[0];
    float* out = (float*)d_out;
    dim3 grid(W / TILE, W / TILE, 8);
    dim3 block(256, 1, 1);
    hipLaunchKernelGGL(nlm_fused, grid, block, 0, stream, rgb, out);
}

// Round 3
// 1192.712 us; speedup vs baseline: 4.9267x; 4.9267x over previous
//
#include <hip/hip_runtime.h>

// NonLocalMeans: rgb (8,3,1024,1024) f32, search 11x11, patch 5x5, circular.
// out(p) = sum_s w(p,s)*rgb(p-s) / sum_s w(p,s),
// w(p,s) = exp(-sqrt(box5x5((y - y_shift)^2)) * inv_h)
//
// R3 = R1's proven ladder structure (the only one the 64-VGPR-capped
// allocator has scheduled well: 89% VALUBusy) + the expand-the-square
// algebra proven correct in R2:
//   box((y-y')^2) = A(p) + A(p-s) - 2*cross,  A = box5x5(y^2) shift-indep.
//  - Row work halves: 11 x SQ5 (110 ops) -> 11 x CR5 (55 ops) per row.
//  - A rides in the UNUSED .w of the existing ldsC float4: zero extra LDS
//    (37 KB, 4 blocks/CU unchanged), zero extra FIN vector loads.
//  - FIN adds fmaf(-2,..) + fmax guard (sqrt of cancellation-negative).
// R2 lesson: do NOT restructure the loop (two-pass dx split + function-scope
// partials + multi-plane LDS pointers -> 15.9 GB scratch, 5.4x regression).
// Accumulation order (dy asc, dx asc, rows asc) identical to R1.

#define HW (1024 * 1024)
#define W 1024
#define MASK 1023

constexpr int TILE = 32;
constexpr int YREG = 46;    // TILE + 2*7 (shift 5 + patch 2)
constexpr int YPITCH = 48;
constexpr int CREG = 42;    // TILE + 2*5
// -log2(e) / (1.0 + 1e-6)
constexpr float NEG_C = -1.4426935981939074f;

// 5-tap cross-correlation; c0..c4 in scope at expansion site
#define CR5(W0,W1,W2,W3,W4) \
    fmaf(c4,(W4), fmaf(c3,(W3), fmaf(c2,(W2), fmaf(c1,(W1), c0*(W0)))))

// Load row r = y0-2+RR (LDS row y0+5+RR) and its dy-shifted counterpart,
// produce h0..h10 = horizontal 5-tap cross-correlations for dx = J-5.
// NOT do-while wrapped: h0..h10 must stay in scope for VSET/VADD.
#define ROW_H(RR)                                                           \
    const float* ycp = &ldsY[(y0 + 5 + (RR)) * YPITCH + tx + 5];            \
    const float* ywp = &ldsY[(y0 + 5 + (RR) - dy) * YPITCH + tx];           \
    const float c0=ycp[0],c1=ycp[1],c2=ycp[2],c3=ycp[3],c4=ycp[4];          \
    const float w0 =ywp[0], w1 =ywp[1], w2 =ywp[2], w3 =ywp[3], w4 =ywp[4]; \
    const float w5 =ywp[5], w6 =ywp[6], w7 =ywp[7], w8 =ywp[8], w9 =ywp[9]; \
    const float w10=ywp[10],w11=ywp[11],w12=ywp[12],w13=ywp[13],w14=ywp[14];\
    const float h0  = CR5(w10,w11,w12,w13,w14);                             \
    const float h1  = CR5(w9, w10,w11,w12,w13);                             \
    const float h2  = CR5(w8, w9, w10,w11,w12);                             \
    const float h3  = CR5(w7, w8, w9, w10,w11);                             \
    const float h4  = CR5(w6, w7, w8, w9, w10);                             \
    const float h5  = CR5(w5, w6, w7, w8, w9);                              \
    const float h6  = CR5(w4, w5, w6, w7, w8);                              \
    const float h7  = CR5(w3, w4, w5, w6, w7);                              \
    const float h8  = CR5(w2, w3, w4, w5, w6);                              \
    const float h9  = CR5(w1, w2, w3, w4, w5);                              \
    const float h10 = CR5(w0, w1, w2, w3, w4);

// partial vertical cross-corr accumulators, 11 per output row, named scalars
#define VDECL(VD) float VD##_0, VD##_1, VD##_2, VD##_3, VD##_4, VD##_5,     \
                        VD##_6, VD##_7, VD##_8, VD##_9, VD##_10
#define VSET(VD)  VD##_0 =h0; VD##_1 =h1; VD##_2 =h2; VD##_3 =h3;           \
                  VD##_4 =h4; VD##_5 =h5; VD##_6 =h6; VD##_7 =h7;           \
                  VD##_8 =h8; VD##_9 =h9; VD##_10=h10
#define VADD(VD)  VD##_0 +=h0; VD##_1 +=h1; VD##_2 +=h2; VD##_3 +=h3;       \
                  VD##_4 +=h4; VD##_5 +=h5; VD##_6 +=h6; VD##_7 +=h7;       \
                  VD##_8 +=h8; VD##_9 +=h9; VD##_10+=h10

// finalize one (YO,J): S = Ac + Aw - 2*cross, clamp, sqrt, exp2, accumulate
#define FIN1(YO, VD, J) do {                                                \
    float4 px = crow[-(J)];                                                 \
    float s = fmaf(-2.0f, VD##_##J, acb + px.w);                            \
    s = fmaxf(s, 0.0f);                                                     \
    float dist = __builtin_amdgcn_sqrtf(s);                                 \
    float wgt  = __builtin_amdgcn_exp2f(dist * NEG_C);                      \
    aR##YO = fmaf(wgt, px.x, aR##YO);                                       \
    aG##YO = fmaf(wgt, px.y, aG##YO);                                       \
    aB##YO = fmaf(wgt, px.z, aB##YO);                                       \
    aW##YO += wgt;                                                          \
} while (0)

// output row YO complete for this dy; frees VD
#define FIN(YO, VD) do {                                                    \
    const float4* crow = &ldsC[(y0 + (YO) - dy + 5) * CREG + tx + 10];      \
    const float acb = ldsC[(y0 + (YO) + 5) * CREG + tx + 5].w;              \
    FIN1(YO,VD,0); FIN1(YO,VD,1); FIN1(YO,VD,2); FIN1(YO,VD,3);             \
    FIN1(YO,VD,4); FIN1(YO,VD,5); FIN1(YO,VD,6); FIN1(YO,VD,7);             \
    FIN1(YO,VD,8); FIN1(YO,VD,9); FIN1(YO,VD,10);                           \
} while (0)

#define STORE(YO) do {                                                      \
    const int off = (by0 + y0 + (YO)) * W + bx0 + tx;                       \
    const float inv = 1.0f / aW##YO;                                        \
    obase[off]          = aR##YO * inv;                                     \
    obase[off + HW]     = aG##YO * inv;                                     \
    obase[off + 2 * HW] = aB##YO * inv;                                     \
} while (0)

// squared 5-tap row sum for the A-field precompute
#define A5(p) fmaf((p)[4],(p)[4], fmaf((p)[3],(p)[3], fmaf((p)[2],(p)[2],   \
              fmaf((p)[1],(p)[1], (p)[0]*(p)[0]))))

__global__ void __launch_bounds__(256) __attribute__((amdgpu_waves_per_eu(4, 4)))
nlm_fused(const float* __restrict__ rgb, float* __restrict__ out) {
    __shared__ float  ldsY[YREG * YPITCH];      // 8832 B
    __shared__ float4 ldsC[CREG * CREG];        // 28224 B  (.w = box5x5(y^2))

    const int tid = threadIdx.x;
    const int batch = blockIdx.z;
    const int by0 = blockIdx.y * TILE;
    const int bx0 = blockIdx.x * TILE;

    const float* base = rgb + (size_t)batch * 3 * HW;

    // ---- stage luminance tile (mean over channels), halo 7 ----
    for (int i = tid; i < YREG * YREG; i += 256) {
        int ry = i / YREG, rx = i - ry * YREG;
        int gy = (by0 + ry - 7) & MASK;
        int gx = (bx0 + rx - 7) & MASK;
        int off = gy * W + gx;
        float v = (base[off] + base[off + HW] + base[off + 2 * HW]) * (1.0f / 3.0f);
        ldsY[ry * YPITCH + rx] = v;
    }
    __syncthreads();    // Y complete before A-field compute

    // ---- stage rgb tile as float4 (halo 5), .w = A = box5x5(y^2) ----
    for (int i = tid; i < CREG * CREG; i += 256) {
        int ry = i / CREG, rx = i - ry * CREG;
        int gy = (by0 + ry - 5) & MASK;
        int gx = (bx0 + rx - 5) & MASK;
        int off = gy * W + gx;
        const float* yb = &ldsY[ry * YPITCH + rx];   // A window = Y rows ry..ry+4
        float a =  A5(yb);
        a += A5(yb + YPITCH);
        a += A5(yb + 2 * YPITCH);
        a += A5(yb + 3 * YPITCH);
        a += A5(yb + 4 * YPITCH);
        ldsC[i] = make_float4(base[off], base[off + HW], base[off + 2 * HW], a);
    }
    __syncthreads();

    const int tx = tid & 31;          // output column within tile
    const int y0 = (tid >> 5) * 4;    // 4-pixel column run per thread

    float aR0=0.f, aG0=0.f, aB0=0.f, aW0=0.f;
    float aR1=0.f, aG1=0.f, aB1=0.f, aW1=0.f;
    float aR2=0.f, aG2=0.f, aB2=0.f, aW2=0.f;
    float aR3=0.f, aG3=0.f, aB3=0.f, aW3=0.f;

    #pragma clang loop unroll(disable)
    for (int dy = -5; dy <= 5; ++dy) {
        VDECL(v0); VDECL(v1); VDECL(v2); VDECL(v3);
        { ROW_H(0); VSET(v0); }
        { ROW_H(1); VADD(v0); VSET(v1); }
        { ROW_H(2); VADD(v0); VADD(v1); VSET(v2); }
        { ROW_H(3); VADD(v0); VADD(v1); VADD(v2); VSET(v3); }
        { ROW_H(4); VADD(v0); VADD(v1); VADD(v2); VADD(v3); }
        FIN(0, v0);
        { ROW_H(5); VADD(v1); VADD(v2); VADD(v3); }
        FIN(1, v1);
        { ROW_H(6); VADD(v2); VADD(v3); }
        FIN(2, v2);
        { ROW_H(7); VADD(v3); }
        FIN(3, v3);
    }

    float* obase = out + (size_t)batch * 3 * HW;
    STORE(0);
    STORE(1);
    STORE(2);
    STORE(3);
}

extern "C" void kernel_launch(void* const* d_in, const int* in_sizes, int n_in,
                              void* d_out, int out_size, void* d_ws, size_t ws_size,
                              hipStream_t stream) {
    const float* rgb = (const float*)d_in[0];
    float* out = (float*)d_out;
    dim3 grid(W / TILE, W / TILE, 8);
    dim3 block(256, 1, 1);
    hipLaunchKernelGGL(nlm_fused, grid, block, 0, stream, rgb, out);
}